// Round 1
// baseline (873.240 us; speedup 1.0000x reference)
//
#include <hip/hip_runtime.h>

typedef __attribute__((ext_vector_type(8))) short bf16x8;
typedef __attribute__((ext_vector_type(4))) float f32x4;
typedef unsigned short u16;

// async global->LDS, 16B per lane, dest = uniform base + lane*16
#define GLOAD16(gsrc, ldst) \
  __builtin_amdgcn_global_load_lds((const __attribute__((address_space(1))) unsigned int*)(gsrc), \
                                   (__attribute__((address_space(3))) unsigned int*)(ldst), 16, 0, 0)

__device__ __forceinline__ u16 f2bf(float f) {
  union { float f; unsigned u; } a; a.f = f;
  unsigned r = a.u + 0x7FFFu + ((a.u >> 16) & 1u);
  return (u16)(r >> 16);
}

// ---------------- convert x (fp32 -> bf16), vectorized ----------------
__global__ __launch_bounds__(256) void k_cvt_x(const float4* __restrict__ x, ushort4* __restrict__ xb) {
  int i = blockIdx.x * 256 + threadIdx.x;
  float4 t = x[i];
  ushort4 o;
  o.x = f2bf(t.x); o.y = f2bf(t.y); o.z = f2bf(t.z); o.w = f2bf(t.w);
  xb[i] = o;
}

// ------------- transpose+convert weights: w[k][n] -> wT[n][k] bf16 -------------
__global__ __launch_bounds__(256) void k_cvt_w(const float* __restrict__ wqkv, const float* __restrict__ wproj,
                                               u16* __restrict__ wqkvT, u16* __restrict__ wprojT) {
  int t = blockIdx.x * 256 + threadIdx.x;      // 0 .. 1048575
  if (t < 786432) {                            // 1536 x 512
    int n = t >> 9, k = t & 511;
    wqkvT[t] = f2bf(wqkv[k * 1536 + n]);
  } else {                                     // 512 x 512
    int u = t - 786432;
    int n = u >> 9, k = u & 511;
    wprojT[u] = f2bf(wproj[k * 512 + n]);
  }
}

// ---------------- 128x128 bf16 MFMA GEMM, K=512, B^T input ----------------
// EPI=0: scatter into q/k/v [B][H][L][HD] bf16.  EPI=1: fp32 out row-major.
template <int EPI>
__global__ __launch_bounds__(256, 2) void k_gemm(const char* __restrict__ A, const char* __restrict__ Bt,
                                                 u16* __restrict__ q, u16* __restrict__ kmat,
                                                 u16* __restrict__ v, float* __restrict__ outf) {
  __shared__ u16 ldsA[128 * 64];
  __shared__ u16 ldsB[128 * 64];
  const int tid = threadIdx.x, lane = tid & 63, wid = tid >> 6;
  const int wm = wid >> 1, wn = wid & 1;
  const int m0 = (blockIdx.x % 784) * 128;
  const int n0 = (blockIdx.x / 784) * 128;

  // staging: linear LDS dest, pre-swizzled global source (XOR (row&7)<<4 on the 128B row)
  size_t srcA[4], srcB[4];
  int dstoff[4];
#pragma unroll
  for (int ci = 0; ci < 4; ++ci) {
    int o = wid * 4096 + ci * 1024 + lane * 16;
    int row = o >> 7;                       // 128 bytes per row (64 bf16)
    int cb = (o & 127) ^ ((row & 7) << 4);
    srcA[ci] = (size_t)(m0 + row) * 1024 + cb;   // global row stride = 512*2 = 1024B
    srcB[ci] = (size_t)(n0 + row) * 1024 + cb;
    dstoff[ci] = (wid * 4 + ci) * 1024;
  }

  f32x4 zero = {0.f, 0.f, 0.f, 0.f};
  f32x4 acc[4][4];
#pragma unroll
  for (int mi = 0; mi < 4; ++mi)
#pragma unroll
    for (int ni = 0; ni < 4; ++ni) acc[mi][ni] = zero;

  const int swz = (lane & 7) << 4;          // (row&7)<<4, row = ..16*j + (lane&15)
  const int cfb = (lane >> 4) << 4;         // fragment k-offset bytes

  for (int kt = 0; kt < 8; ++kt) {
    size_t kb = (size_t)kt * 128;
#pragma unroll
    for (int ci = 0; ci < 4; ++ci) GLOAD16(A + srcA[ci] + kb, (char*)ldsA + dstoff[ci]);
#pragma unroll
    for (int ci = 0; ci < 4; ++ci) GLOAD16(Bt + srcB[ci] + kb, (char*)ldsB + dstoff[ci]);
    __syncthreads();
#pragma unroll
    for (int kk2 = 0; kk2 < 2; ++kk2) {
      bf16x8 af[4], bfr[4];
#pragma unroll
      for (int i = 0; i < 4; ++i) {
        int rowA = wm * 64 + i * 16 + (lane & 15);
        af[i] = *(const bf16x8*)((const char*)ldsA + rowA * 128 + ((cfb + kk2 * 64) ^ swz));
        int rowB = wn * 64 + i * 16 + (lane & 15);
        bfr[i] = *(const bf16x8*)((const char*)ldsB + rowB * 128 + ((cfb + kk2 * 64) ^ swz));
      }
#pragma unroll
      for (int mi = 0; mi < 4; ++mi)
#pragma unroll
        for (int ni = 0; ni < 4; ++ni)
          acc[mi][ni] = __builtin_amdgcn_mfma_f32_16x16x32_bf16(af[mi], bfr[ni], acc[mi][ni], 0, 0, 0);
    }
    __syncthreads();
  }

  // epilogue: C layout col=lane&15, row=(lane>>4)*4+reg
#pragma unroll
  for (int mi = 0; mi < 4; ++mi) {
#pragma unroll
    for (int r = 0; r < 4; ++r) {
      int rowt = m0 + wm * 64 + mi * 16 + ((lane >> 4) << 2) + r;
      if (EPI == 0) {
        int b = rowt / 49;
        int ll = rowt - b * 49;
#pragma unroll
        for (int ni = 0; ni < 4; ++ni) {
          int coln = n0 + wn * 64 + ni * 16 + (lane & 15);
          int which = coln >> 9, h = (coln >> 5) & 15, d = coln & 31;
          u16* dst = (which == 0) ? q : ((which == 1) ? kmat : v);
          dst[(((size_t)b * 16 + h) * 49 + ll) * 32 + d] = f2bf(acc[mi][ni][r]);
        }
      } else {
#pragma unroll
        for (int ni = 0; ni < 4; ++ni) {
          int coln = n0 + wn * 64 + ni * 16 + (lane & 15);
          outf[(size_t)rowt * 512 + coln] = acc[mi][ni][r];
        }
      }
    }
  }
}

// ---------------- attention: one wave per (window b, head h) ----------------
__global__ __launch_bounds__(256, 2) void k_attn(const u16* __restrict__ q, const u16* __restrict__ kmat,
                                                 const u16* __restrict__ v, const float* __restrict__ mask,
                                                 const float* __restrict__ bias_table,
                                                 u16* __restrict__ attnout) {
  __shared__ u16 Plds[4][64 * 72];   // per-wave P, stride 72 (16B-aligned rows, bank-spread)
  const int lane = threadIdx.x & 63, wid = threadIdx.x >> 6;
  const int task = blockIdx.x * 4 + wid;          // < 32768
  const int b = task >> 4, h = task & 15;
  const int g = lane >> 4, c = lane & 15;
  const u16* qb = q + (size_t)task * 1568;        // [49][32]
  const u16* kb = kmat + (size_t)task * 1568;
  const u16* vb = v + (size_t)task * 1568;

  bf16x8 zv = {0, 0, 0, 0, 0, 0, 0, 0};
  bf16x8 qf[4], kf[4];
#pragma unroll
  for (int i = 0; i < 4; ++i) {
    int row = i * 16 + c;
    qf[i] = (row < 49) ? *(const bf16x8*)(qb + row * 32 + g * 8) : zv;
    kf[i] = (row < 49) ? *(const bf16x8*)(kb + row * 32 + g * 8) : zv;
  }

  f32x4 zero = {0.f, 0.f, 0.f, 0.f};
  f32x4 S[4][4];
#pragma unroll
  for (int mi = 0; mi < 4; ++mi)
#pragma unroll
    for (int ni = 0; ni < 4; ++ni)
      S[mi][ni] = __builtin_amdgcn_mfma_f32_16x16x32_bf16(qf[mi], kf[ni], zero, 0, 0, 0);

  // bias + mask + softmax (wave-parallel: 16-lane butterflies)
  const float* maskw = mask + (size_t)(b & 63) * 2401;
  int keyc[4], jh[4], jw[4];
  bool kval[4];
#pragma unroll
  for (int ni = 0; ni < 4; ++ni) {
    int key = ni * 16 + c;
    kval[ni] = key < 49;
    int kc = kval[ni] ? key : 48;
    keyc[ni] = kc;
    jh[ni] = kc / 7;
    jw[ni] = kc - jh[ni] * 7;
  }
#pragma unroll
  for (int mi = 0; mi < 4; ++mi) {
#pragma unroll
    for (int r = 0; r < 4; ++r) {
      int qrow = mi * 16 + g * 4 + r;
      int qc = qrow < 49 ? qrow : 48;
      int ih = qc / 7, iw = qc - ih * 7;
      const float* mrow = maskw + qc * 49;
      float vals[4], vmax = -3.0e30f;
#pragma unroll
      for (int ni = 0; ni < 4; ++ni) {
        float sv = -3.0e30f;
        if (kval[ni]) {
          int ridx = (ih - jh[ni] + 6) * 13 + (iw - jw[ni] + 6);
          sv = S[mi][ni][r] * 0.17677669529663687f + bias_table[ridx * 16 + h] + mrow[keyc[ni]];
        }
        vals[ni] = sv;
        vmax = fmaxf(vmax, sv);
      }
#pragma unroll
      for (int mk = 1; mk < 16; mk <<= 1) vmax = fmaxf(vmax, __shfl_xor(vmax, mk, 64));
      float ssum = 0.f, e[4];
#pragma unroll
      for (int ni = 0; ni < 4; ++ni) { e[ni] = __expf(vals[ni] - vmax); ssum += e[ni]; }
#pragma unroll
      for (int mk = 1; mk < 16; mk <<= 1) ssum += __shfl_xor(ssum, mk, 64);
      float inv = 1.f / ssum;
#pragma unroll
      for (int ni = 0; ni < 4; ++ni)
        Plds[wid][qrow * 72 + ni * 16 + c] = f2bf(e[ni] * inv);
    }
  }

  // PV: A-frags of P from LDS (contiguous), B-frags of V assembled from global
  f32x4 o[4][2];
#pragma unroll
  for (int mi = 0; mi < 4; ++mi) { o[mi][0] = zero; o[mi][1] = zero; }
#pragma unroll
  for (int kk2 = 0; kk2 < 2; ++kk2) {
    bf16x8 af[4];
#pragma unroll
    for (int mi = 0; mi < 4; ++mi)
      af[mi] = *(const bf16x8*)(&Plds[wid][(mi * 16 + c) * 72 + kk2 * 32 + g * 8]);
    bf16x8 vf[2];
#pragma unroll
    for (int nd = 0; nd < 2; ++nd) {
#pragma unroll
      for (int j = 0; j < 8; ++j) {
        int kk = kk2 * 32 + g * 8 + j;
        vf[nd][j] = (kk < 49) ? (short)vb[kk * 32 + nd * 16 + c] : (short)0;
      }
    }
#pragma unroll
    for (int mi = 0; mi < 4; ++mi)
#pragma unroll
      for (int nd = 0; nd < 2; ++nd)
        o[mi][nd] = __builtin_amdgcn_mfma_f32_16x16x32_bf16(af[mi], vf[nd], o[mi][nd], 0, 0, 0);
  }

  // write attnout [B][L][C] bf16, channel = h*32 + d
#pragma unroll
  for (int mi = 0; mi < 4; ++mi) {
#pragma unroll
    for (int r = 0; r < 4; ++r) {
      int qrow = mi * 16 + g * 4 + r;
      if (qrow < 49) {
        size_t base = ((size_t)b * 49 + qrow) * 512 + h * 32;
        attnout[base + 0 * 16 + c] = f2bf(o[mi][0][r]);
        attnout[base + 1 * 16 + c] = f2bf(o[mi][1][r]);
      }
    }
  }
}

extern "C" void kernel_launch(void* const* d_in, const int* in_sizes, int n_in,
                              void* d_out, int out_size, void* d_ws, size_t ws_size,
                              hipStream_t stream) {
  const float* x = (const float*)d_in[0];
  const float* mask = (const float*)d_in[1];
  const float* bias_table = (const float*)d_in[2];
  const float* w_qkv = (const float*)d_in[3];
  const float* w_proj = (const float*)d_in[4];
  float* out = (float*)d_out;

  char* ws = (char*)d_ws;
  u16* xb     = (u16*)(ws);                  // 102,760,448 B ; reused as attnout
  u16* q      = (u16*)(ws + 102760448);
  u16* km     = (u16*)(ws + 205520896);
  u16* v      = (u16*)(ws + 308281344);
  u16* wqkvT  = (u16*)(ws + 411041792);      // 1,572,864 B
  u16* wprojT = (u16*)(ws + 412614656);      //   524,288 B  -> total 413,138,944 B

  k_cvt_x<<<50176, 256, 0, stream>>>((const float4*)x, (ushort4*)xb);
  k_cvt_w<<<4096, 256, 0, stream>>>(w_qkv, w_proj, wqkvT, wprojT);
  k_gemm<0><<<784 * 12, 256, 0, stream>>>((const char*)xb, (const char*)wqkvT, q, km, v, nullptr);
  u16* attnout = xb;
  k_attn<<<8192, 256, 0, stream>>>(q, km, v, mask, bias_table, attnout);
  k_gemm<1><<<784 * 4, 256, 0, stream>>>((const char*)attnout, (const char*)wprojT,
                                         nullptr, nullptr, nullptr, out);
}